// Round 1
// baseline (247.304 us; speedup 1.0000x reference)
//
#include <hip/hip_runtime.h>

// ---------------------------------------------------------------------------
// YOLO NMS post-processing for MI355X.
// Pipeline: scores (LDS-staged, 2 thr/row) + 8-way sliced histogram ->
// fused reduce+select (single block; winner walks its per-bucket sums held in
// registers, no global hist) -> compact candidates (bucket >= B, also zeroes
// rank[]) -> exact rank-by-counting -> scatter by rank (+box decode) ->
// PACKED upper-triangular 64x64 IoU bitmask (row-block w keeps only words
// w..63; lower triangle never materialized) + a separate 64x64 diagonal-block
// array -> single-wave greedy scan:
//   * decisions per batch use ONLY the diagonal block: wave-uniform scalar
//     chain ctz -> readlane64 -> andn2 (~10cy per KEPT row, no ballot)
//   * full packed rows are ds_read only for KEPT rows (off critical path)
//   * batch handoff: variable-length DMA (L(w)=ceil((64-w)/2) KB) with an
//     exact-immediate `s_waitcnt vmcnt(p)` switch, p = loads of batch w+1 in
//     flight. Issue order is monotone so the invariant survives skipped dead
//     batches; the only full drain is the final __syncthreads.
// All IoU-relevant fp32 math uses _rn intrinsics so hipcc's default
// -ffp-contract=fast cannot fuse mul+add into fma (must match numpy fp32).
// ---------------------------------------------------------------------------

#define AS1 __attribute__((address_space(1)))
#define AS3 __attribute__((address_space(3)))

constexpr int    N_ANCH = 100800;
constexpr int    DIMV   = 117;   // 4 box + 1 obj + 80 cls + 32 mask
constexpr int    TOPKN  = 4096;
constexpr int    MAXDET = 300;
constexpr int    KCAP   = 12288; // candidate capacity
constexpr int    NBUCK  = 16384; // scores < 1.0 -> bits>>16 < 0x3F80 < 16384
constexpr int    NSLICE = 8;

// packed mask geometry: row-block w (rows [64w,64w+64)) stores words w..63
// contiguously: 64 rows x (64-w) u64. pbase64(w) = 64 * sum_{k<w}(64-k).
constexpr int PACK_TOT = 133120;                  // 64 * 2080 u64 = 1,064,960 B

// workspace layout (bytes)
constexpr size_t WS_SLICES = 0;                                   // 8*16384 u32
constexpr size_t WS_SCORES = WS_SLICES + (size_t)NSLICE * NBUCK * 4;
constexpr size_t WS_CLS    = WS_SCORES + (size_t)N_ANCH * 4;
constexpr size_t WS_SEL    = WS_CLS    + (size_t)N_ANCH * 4;      // 64 i32
constexpr size_t WS_KEYS   = WS_SEL    + 256;                     // 12288 u64
constexpr size_t WS_RANK   = WS_KEYS   + (size_t)KCAP * 8;        // 12288 i32
constexpr size_t WS_SIDX   = WS_RANK   + (size_t)KCAP * 4;        // 4096 i32
constexpr size_t WS_SSC    = WS_SIDX   + 4096ull * 4;             // 4096 f32
constexpr size_t WS_BOXES  = WS_SSC    + 4096ull * 4;             // 4096*4 f32
constexpr size_t WS_MASKP  = WS_BOXES  + 4096ull * 16;            // packed mask
constexpr size_t WS_DIAG   = WS_MASKP  + (size_t)PACK_TOT * 8 + 4096; // +DMA pad
constexpr size_t WS_OUTI   = WS_DIAG   + 4096ull * 8;             // 300 i32
constexpr size_t WS_OUTS   = WS_OUTI   + 1280;                    // 300 f32

__global__ void zero_kernel(unsigned* __restrict__ slices, int* __restrict__ sel) {
    int i = blockIdx.x * 256 + threadIdx.x;
    if (i < NSLICE * NBUCK) slices[i] = 0u;
    if (i < 64)             sel[i]    = 0;
}

// 64 rows per 128-thread block, staged to LDS with coalesced float4 loads.
// 2 threads per row: even lane scans classes 0..39, odd lane 40..79, merged
// via shfl_xor. Strict > keeps the first (lowest-class) argmax like numpy.
// Histogram atomics go to slice (blockIdx & 7) to spread hot-line contention.
constexpr int SROWS = 64;
__global__ void score_kernel(const float* __restrict__ x, float* __restrict__ scores,
                             int* __restrict__ cls, unsigned* __restrict__ slices) {
    __shared__ float sx[SROWS * DIMV];           // 29952 B
    int block0 = blockIdx.x * SROWS;
    const float4* src = (const float4*)(x + (size_t)block0 * DIMV); // 64*468 % 16 == 0
    float4* dst = (float4*)sx;
    constexpr int NV4 = SROWS * DIMV / 4;        // 1872
    for (int i = threadIdx.x; i < NV4; i += 128) dst[i] = src[i];
    __syncthreads();
    int row  = threadIdx.x >> 1;
    int half = threadIdx.x & 1;
    const float* rp = sx + row * DIMV;
    float obj = rp[4];
    const float* cp = rp + 5 + half * 40;
    float best = -1.0f;
    int   bc   = half * 40;
#pragma unroll 8
    for (int c = 0; c < 40; ++c) {
        float s = __fmul_rn(cp[c], obj);
        if (s > best) { best = s; bc = half * 40 + c; }
    }
    float so = __shfl_xor(best, 1);
    int   co = __shfl_xor(bc, 1);
    if (half == 0) {
        if (so > best) { best = so; bc = co; }   // strict >: even (lower classes) wins ties
        int a = block0 + row;
        bool valid = obj > 0.25f;
        scores[a] = valid ? best : -1.0f;
        cls[a]    = bc;
        if (valid) {
            unsigned b = __float_as_uint(best) >> 16;   // < 16384 (best in [0,1))
            atomicAdd(&slices[(blockIdx.x & (NSLICE - 1)) * NBUCK + b], 1u);
        }
    }
}

// fused reduce+select, one 1024-thread block. Each thread owns 16 buckets
// (chunk t covers [NBUCK-16(t+1), ..+16), t=0 = top), sums them across the 8
// slices into registers, scans chunk totals, and the boundary-owning thread
// walks ITS OWN register copy descending. Finds bucket B with
// cntAbove(B) < 4096 <= cntAbove(B) + hist[B]. No global hist array.
__global__ void select_kernel(const unsigned* __restrict__ slices, int* sel) {
    __shared__ unsigned sv[1024];
    int t = threadIdx.x;
    int base = NBUCK - 16 * (t + 1);
    unsigned hb[16];
#pragma unroll
    for (int k = 0; k < 16; ++k) hb[k] = 0u;
    for (int s = 0; s < NSLICE; ++s) {
        const uint4* hp = (const uint4*)(slices + (size_t)s * NBUCK + base);
#pragma unroll
        for (int q = 0; q < 4; ++q) {
            uint4 v = hp[q];
            hb[q * 4 + 0] += v.x; hb[q * 4 + 1] += v.y;
            hb[q * 4 + 2] += v.z; hb[q * 4 + 3] += v.w;
        }
    }
    unsigned own = 0;
#pragma unroll
    for (int k = 0; k < 16; ++k) own += hb[k];
    sv[t] = own;
    __syncthreads();
    for (int off = 1; off < 1024; off <<= 1) { // inclusive scan (descending-chunk order)
        unsigned v = (t >= off) ? sv[t - off] : 0u;
        __syncthreads();
        sv[t] += v;
        __syncthreads();
    }
    unsigned incl = sv[t];
    unsigned before = incl - own;
    if (before < (unsigned)TOPKN && incl >= (unsigned)TOPKN) {
        unsigned running = before;
        for (int k = 15; k >= 0; --k) {        // walk own buckets descending
            running += hb[k];
            if (running >= (unsigned)TOPKN) {
                sel[0] = base + k;
                sel[1] = (int)(running - hb[k]);
                break;
            }
        }
    }
}

// compact all anchors with bucket >= B into keys[]; key = (score_bits<<32)|~a
// -> descending key order == (score desc, idx asc) == stable top_k order.
// Also zeroes rank[] (runs strictly before rank_kernel on the stream).
__global__ void compact_kernel(const float* __restrict__ scores, int* sel,
                               unsigned long long* __restrict__ keys,
                               int* __restrict__ rank) {
    int a = blockIdx.x * blockDim.x + threadIdx.x;
    if (a < KCAP) rank[a] = 0;
    if (a >= N_ANCH) return;
    float s = scores[a];
    if (s < 0.0f) return;
    unsigned bits = __float_as_uint(s);
    if ((int)(bits >> 16) < sel[0]) return;
    int pos = atomicAdd(&sel[2], 1);
    if (pos < KCAP) keys[pos] = ((unsigned long long)bits << 32) | (unsigned)(~a);
}

// exact rank by counting: rank[i] = #{j : key_j > key_i}. Keys unique ->
// ranks are a permutation; ranks 0..4095 are the sorted top-4096.
// 8 column slabs; blocks past n exit immediately (n ~ 4.5k << KCAP).
constexpr int NCOLP = 8;
__global__ void rank_kernel(const unsigned long long* __restrict__ keys,
                            const int* __restrict__ sel, int* __restrict__ rank) {
    __shared__ unsigned long long tile[2048];
    int n = sel[2]; if (n > KCAP) n = KCAP;
    if (blockIdx.x * 256 >= n) return;           // no owning keys in this block
    int t0 = blockIdx.y * 2048;                  // 2048*8 = 16384 >= KCAP: one tile
    if (t0 >= n) return;                         // empty column slab
    int i = blockIdx.x * 256 + threadIdx.x;
    unsigned long long myKey = (i < n) ? keys[i] : 0ull;
    int m = n - t0; if (m > 2048) m = 2048;
    for (int j = threadIdx.x; j < m; j += 256) tile[j] = keys[t0 + j];
    __syncthreads();
    int cnt = 0;
    int j = 0;
    for (; j + 3 < m; j += 4) {
        cnt += (tile[j]     > myKey);
        cnt += (tile[j + 1] > myKey);
        cnt += (tile[j + 2] > myKey);
        cnt += (tile[j + 3] > myKey);
    }
    for (; j < m; ++j) cnt += (tile[j] > myKey);
    if (i < n && cnt) atomicAdd(&rank[i], cnt);
}

// place keys by rank; also decode the yxyx box for the sorted slot (no fma).
__global__ void scatter_kernel(const float* __restrict__ x,
                               const unsigned long long* __restrict__ keys,
                               const int* __restrict__ sel, const int* __restrict__ rank,
                               int* __restrict__ sidx, float* __restrict__ sscore,
                               float* __restrict__ boxes) {
    int n = sel[2]; if (n > KCAP) n = KCAP;
    int i = blockIdx.x * 256 + threadIdx.x;
    if (i >= n) return;
    int r = rank[i];
    if (r >= TOPKN) return;
    unsigned long long k = keys[i];
    int a = (int)(~(unsigned)(k & 0xFFFFFFFFull));
    sidx[r]   = a;
    sscore[r] = __uint_as_float((unsigned)(k >> 32));
    const float* p = x + (size_t)a * DIMV;
    float xc = p[0], yc = p[1], w = p[2], h = p[3];
    float hw = __fmul_rn(w, 0.5f);
    float hh = __fmul_rn(h, 0.5f);
    boxes[r * 4 + 0] = __fsub_rn(yc, hh);
    boxes[r * 4 + 1] = __fsub_rn(xc, hw);
    boxes[r * 4 + 2] = __fadd_rn(yc, hh);
    boxes[r * 4 + 3] = __fadd_rn(xc, hw);
}

// 64x64 tile IoU bitmask, PACKED upper triangle only. Row-block rowT stores
// words rowT..63: row r=64*rowT+t word colT lives at
//   maskp[pbase64(rowT) + t*(64-rowT) + (colT-rowT)].
// Diagonal blocks (colT==rowT) additionally go to diag[rowT*64+t] (the scan's
// in-batch decision matrix). Lower-triangle blocks write NOTHING.
__global__ void iou_mask_kernel(const float* __restrict__ boxes,
                                unsigned long long* __restrict__ maskp,
                                unsigned long long* __restrict__ diag) {
    int colT = blockIdx.x, rowT = blockIdx.y;
    if (colT < rowT) return;                 // never materialized
    int t = threadIdx.x;                     // 0..63
    __shared__ float cb[64][5];
    const float4* bp = (const float4*)boxes; // y1 x1 y2 x2, 16B-aligned
    int cj = colT * 64 + t;
    {
        float4 c = bp[cj];
        cb[t][0] = c.x; cb[t][1] = c.y; cb[t][2] = c.z; cb[t][3] = c.w;
        cb[t][4] = __fmul_rn(__fsub_rn(c.z, c.x), __fsub_rn(c.w, c.y));
    }
    __syncthreads();
    int r = rowT * 64 + t;
    float4 rv = bp[r];
    float ry1 = rv.x, rx1 = rv.y, ry2 = rv.z, rx2 = rv.w;
    float rarea = __fmul_rn(__fsub_rn(ry2, ry1), __fsub_rn(rx2, rx1));
    unsigned long long bitsw = 0ull;
#pragma unroll 8
    for (int j = 0; j < 64; ++j) {
        float iy1 = fmaxf(ry1, cb[j][0]);
        float ix1 = fmaxf(rx1, cb[j][1]);
        float iy2 = fminf(ry2, cb[j][2]);
        float ix2 = fminf(rx2, cb[j][3]);
        float ih = fmaxf(__fsub_rn(iy2, iy1), 0.0f);
        float iw = fmaxf(__fsub_rn(ix2, ix1), 0.0f);
        float inter = __fmul_rn(ih, iw);
        float uni = __fsub_rn(__fadd_rn(rarea, cb[j][4]), inter);
        float iou = __fdiv_rn(inter, fmaxf(uni, 1e-9f));
        if (iou > 0.45f && (colT * 64 + j) > r) bitsw |= (1ull << j);
    }
    int pb = 64 * (64 * rowT - (rowT * (rowT - 1)) / 2);
    maskp[pb + t * (64 - rowT) + (colT - rowT)] = bitsw;
    if (colT == rowT) diag[(rowT << 6) + t] = bitsw;
}

__device__ __forceinline__ unsigned long long readlane64(unsigned long long v, int l) {
    unsigned lo = (unsigned)__builtin_amdgcn_readlane((int)(unsigned)(v & 0xFFFFFFFFull), l);
    unsigned hi = (unsigned)__builtin_amdgcn_readlane((int)(unsigned)(v >> 32), l);
    return ((unsigned long long)hi << 32) | lo;
}

// Single-wave greedy scan over the packed mask. lane j owns remv word j.
// Per batch w (rows [64w,64w+64)):
//   1. issue batch w+1's DMA (L(w+1)=ceil((63-w)/2) KB-loads, monotone order)
//   2. decisions from the diagonal block ONLY: wave-uniform scalar chain
//      b=ctz(alive); keep b; alive &= ~(diag[b] | bit b). No ballot, no
//      dependence on the mask-row ds_reads.
//   3. kept rows' full packed rows OR'd into remv (grouped-4 pipelined
//      ds_reads, lanes j>=w only; words j<w are final and never re-read).
// Handoff: `s_waitcnt vmcnt(p)` with p = exact loads of batch w+1 in flight
// (switch over compile-time immediates). Only the final __syncthreads drains.
__global__ void __launch_bounds__(64, 1)
nms_scan_kernel(const unsigned long long* __restrict__ maskp,
                const unsigned long long* __restrict__ diagG,
                const float* __restrict__ sscore,
                int* __restrict__ outIdx, float* __restrict__ outScore) {
    int lane = threadIdx.x;              // 64 threads = one wave
    unsigned long long remv = 0ull;
    __shared__ __align__(16) unsigned long long tile[2 * 4096];   // 2 x 32 KB
    __shared__ __align__(16) unsigned long long diagLds[4096];    // 32 KB
    __shared__ int keepArr[MAXDET];
    __shared__ unsigned long long remvFinal[64];
    int count = 0;

    // batch w -> buffer w&1; written at iteration w-1 (or prologue), read at
    // iteration w, overwritten at iteration w+1 (strictly after its read).
    auto issueBatch = [&](int w) {
        if (w >= 64) return;
        int L = (65 - w) >> 1;           // ceil((64-w)*512B / 1024B)
        const char* gbase = (const char*)maskp +
                            (size_t)(64 * (64 * w - (w * (w - 1)) / 2)) * 8 +
                            (size_t)lane * 16;
        char* lbase = (char*)tile + (size_t)(w & 1) * 32768;
        for (int i = 0; i < L; ++i) {
            __builtin_amdgcn_global_load_lds(
                (AS1 const unsigned*)(gbase + (size_t)i * 1024),
                (AS3 unsigned*)(lbase + (size_t)i * 1024), 16, 0, 0);
        }
    };

    { // diag DMA first (oldest in queue -> covered by the first batch wait)
        const char* gb = (const char*)diagG + (size_t)lane * 16;
        char* lb = (char*)diagLds;
#pragma unroll
        for (int i = 0; i < 32; ++i) {
            __builtin_amdgcn_global_load_lds(
                (AS1 const unsigned*)(gb + (size_t)i * 1024),
                (AS3 unsigned*)(lb + (size_t)i * 1024), 16, 0, 0);
        }
    }
    issueBatch(0);

#define VW(n) asm volatile("s_waitcnt vmcnt(" #n ")" ::: "memory")

    for (int w = 0; w < 64 && count < MAXDET; ++w) {
        issueBatch(w + 1);
        unsigned long long cand = __shfl(~remv, w);   // wave-uniform
        if (!cand) continue;                          // dead batch: no wait at all
        // batch w (and diag) landed once outstanding <= loads of batch w+1
        int p = (w < 63) ? ((64 - w) >> 1) : 0;
        switch (p) {
            case 32: VW(32); break; case 31: VW(31); break; case 30: VW(30); break;
            case 29: VW(29); break; case 28: VW(28); break; case 27: VW(27); break;
            case 26: VW(26); break; case 25: VW(25); break; case 24: VW(24); break;
            case 23: VW(23); break; case 22: VW(22); break; case 21: VW(21); break;
            case 20: VW(20); break; case 19: VW(19); break; case 18: VW(18); break;
            case 17: VW(17); break; case 16: VW(16); break; case 15: VW(15); break;
            case 14: VW(14); break; case 13: VW(13); break; case 12: VW(12); break;
            case 11: VW(11); break; case 10: VW(10); break; case  9: VW(9);  break;
            case  8: VW(8);  break; case  7: VW(7);  break; case  6: VW(6);  break;
            case  5: VW(5);  break; case  4: VW(4);  break; case  3: VW(3);  break;
            case  2: VW(2);  break; case  1: VW(1);  break; default: VW(0);  break;
        }
        // --- decisions: scalar chain on the diagonal block -----------------
        unsigned long long diagv = diagLds[(w << 6) | lane]; // lane b: row b's in-batch word
        unsigned long long alive = cand;
        unsigned long long keptM = 0ull;
        while (alive && count < MAXDET) {
            int b = (int)__builtin_ctzll(alive);      // wave-uniform
            unsigned long long db = readlane64(diagv, b);
            if (lane == 0) keepArr[count] = (w << 6) + b;
            count++;
            keptM |= (1ull << b);
            alive &= ~(db | (1ull << b));
        }
        // --- OR kept rows' full packed rows into remv (grouped-4) ----------
        const unsigned long long* trow = tile + (size_t)(w & 1) * 4096;
        int stride = 64 - w;
        int rel = lane - w;                           // word j stored at rel >= 0
        while (keptM) {
            int bs[4]; unsigned long long t2 = keptM; int g = 0;
#pragma unroll
            for (int t = 0; t < 4; ++t) {
                bs[t] = t2 ? (int)__builtin_ctzll(t2) : 0;
                if (t2) { t2 &= t2 - 1; g = t + 1; }
            }
            unsigned long long vs[4];
#pragma unroll
            for (int t = 0; t < 4; ++t)               // independent, pipelined ds_reads
                vs[t] = (rel >= 0) ? trow[bs[t] * stride + rel] : 0ull;
#pragma unroll
            for (int t = 0; t < 4; ++t)
                if (t < g) remv |= vs[t];
            keptM = t2;
        }
    }
    __syncthreads();                      // drain outstanding DMA before output
    remvFinal[lane] = remv;
    __syncthreads();
    int K = count;                        // uniform across the wave
    for (int k = lane; k < K; k += 64) {
        int s = keepArr[k];
        outIdx[k] = s;
        outScore[k] = sscore[s];
    }
    if (K < MAXDET && lane == 0) {
        int filled = K;
        for (int w = 0; w < 64 && filled < MAXDET; ++w) {
            unsigned long long word = remvFinal[w];
            while (word && filled < MAXDET) {
                int b = (int)__builtin_ctzll(word);
                word &= word - 1;
                outIdx[filled] = (w << 6) + b;
                outScore[filled] = -1.0f;
                filled++;
            }
        }
    }
}

// emit: boxes[300*4] | classes[300] | scores[300] | masks[300*32]
__global__ void write_out_kernel(const float* __restrict__ x, const int* __restrict__ sidx,
                                 const int* __restrict__ cls, const float* __restrict__ boxes,
                                 const int* __restrict__ outIdx, const float* __restrict__ outScore,
                                 float* __restrict__ out) {
    int o = blockIdx.x;                  // 300
    int t = threadIdx.x;                 // 64
    int s = outIdx[o];
    int a = sidx[s];
    if (t < 32) {
        out[1800 + o * 32 + t] = x[(size_t)a * DIMV + 85 + t];
    } else if (t < 36) {
        out[o * 4 + (t - 32)] = boxes[s * 4 + (t - 32)];
    } else if (t == 36) {
        out[1200 + o] = (float)cls[a];
    } else if (t == 37) {
        out[1500 + o] = outScore[o];
    }
}

extern "C" void kernel_launch(void* const* d_in, const int* in_sizes, int n_in,
                              void* d_out, int out_size, void* d_ws, size_t ws_size,
                              hipStream_t stream) {
    const float* x = (const float*)d_in[0];
    char* ws = (char*)d_ws;
    unsigned*            slices = (unsigned*)(ws + WS_SLICES);
    float*               scores = (float*)(ws + WS_SCORES);
    int*                 cls    = (int*)(ws + WS_CLS);
    int*                 sel    = (int*)(ws + WS_SEL);
    unsigned long long*  keys   = (unsigned long long*)(ws + WS_KEYS);
    int*                 rank   = (int*)(ws + WS_RANK);
    int*                 sidx   = (int*)(ws + WS_SIDX);
    float*               sscore = (float*)(ws + WS_SSC);
    float*               boxes  = (float*)(ws + WS_BOXES);
    unsigned long long*  maskp  = (unsigned long long*)(ws + WS_MASKP);
    unsigned long long*  diag   = (unsigned long long*)(ws + WS_DIAG);
    int*                 outIdx = (int*)(ws + WS_OUTI);
    float*               outSc  = (float*)(ws + WS_OUTS);

    zero_kernel<<<(NSLICE * NBUCK) / 256, 256, 0, stream>>>(slices, sel);
    score_kernel<<<N_ANCH / SROWS, 128, 0, stream>>>(x, scores, cls, slices);
    select_kernel<<<1, 1024, 0, stream>>>(slices, sel);
    compact_kernel<<<(N_ANCH + 255) / 256, 256, 0, stream>>>(scores, sel, keys, rank);
    dim3 rg(KCAP / 256, NCOLP);
    rank_kernel<<<rg, 256, 0, stream>>>(keys, sel, rank);
    scatter_kernel<<<KCAP / 256, 256, 0, stream>>>(x, keys, sel, rank, sidx, sscore, boxes);
    dim3 mg(64, 64);
    iou_mask_kernel<<<mg, 64, 0, stream>>>(boxes, maskp, diag);
    nms_scan_kernel<<<1, 64, 0, stream>>>(maskp, diag, sscore, outIdx, outSc);
    write_out_kernel<<<MAXDET, 64, 0, stream>>>(x, sidx, cls, boxes, outIdx, outSc, (float*)d_out);
}